// Round 6
// baseline (131.348 us; speedup 1.0000x reference)
//
#include <hip/hip_runtime.h>

#define NA 2048
#define NT 256

__device__ __forceinline__ float silu_f(float x) { return x / (1.0f + __expf(-x)); }

__device__ __forceinline__ float wave_reduce(float v) {
    #pragma unroll
    for (int off = 32; off > 0; off >>= 1) v += __shfl_down(v, off, 64);
    return v;
}

// ---------------------------------------------------------------------------
// k1: RBF features + both MLPs, one wave per atom, barrier-free.
// 512 blocks x 256 threads; wave wv of block b owns atom i = b*4 + wv.
// Block 0 also zero-inits out[0] (k2 atomicAdds into it; stream order +
// kernel-boundary release make it visible -- no in-kernel fence needed).
// ---------------------------------------------------------------------------
__global__ __launch_bounds__(NT) void k1_feat_mlp(
    const float* __restrict__ pos,
    const float* __restrict__ cw1, const float* __restrict__ cb1,
    const float* __restrict__ cw2, const float* __restrict__ cb2,
    const float* __restrict__ cw3, const float* __restrict__ cb3,
    const float* __restrict__ ew1, const float* __restrict__ eb1,
    const float* __restrict__ ew2, const float* __restrict__ eb2,
    const float* __restrict__ ew3, const float* __restrict__ eb3,
    float4* __restrict__ pxyzq, float* __restrict__ esr,
    float* __restrict__ out)
{
    const int tid = threadIdx.x, lane = tid & 63, wv = tid >> 6;
    const int i = blockIdx.x * 4 + wv;
    if (blockIdx.x == 0 && tid == 0) out[0] = 0.0f;
    const float pix = pos[3*i], piy = pos[3*i+1], piz = pos[3*i+2];

    float acc[16];
    #pragma unroll
    for (int r = 0; r < 16; ++r) acc[r] = 0.0f;

    for (int j = lane; j < NA; j += 64) {
        float dx = pix - pos[3*j], dy = piy - pos[3*j+1], dz = piz - pos[3*j+2];
        float d2 = dx*dx + dy*dy + dz*dz;
        if (d2 > 0.0f && d2 < 25.0f) {
            float d  = sqrtf(d2);
            float sm = 0.5f * (1.0f + __cosf(0.6283185307179586f * d)); // cos(pi*d/5)
            #pragma unroll
            for (int r = 0; r < 16; ++r) {
                float t = d - (0.5f + 0.3f * (float)r);   // centers linspace(0.5,5,16)
                acc[r] += sm * __expf(-t * t * 25.28395061728395f); // 1/(2 eta^2)
            }
        }
    }

    // reduce to lane 0 then broadcast: every lane gets the full feature vector
    float feat[16];
    #pragma unroll
    for (int r = 0; r < 16; ++r) {
        float v = wave_reduce(acc[r]);
        feat[r] = __shfl(v, 0, 64);
    }

    // both MLPs sequentially; lane = hidden unit index
    float oq = 0.0f, oe = 0.0f;
    #pragma unroll
    for (int which = 0; which < 2; ++which) {
        const float* w1 = which ? ew1 : cw1;
        const float* b1 = which ? eb1 : cb1;
        const float* w2 = which ? ew2 : cw2;
        const float* b2 = which ? eb2 : cb2;
        const float* w3 = which ? ew3 : cw3;

        float s = b1[lane];
        #pragma unroll
        for (int r = 0; r < 16; ++r) s += feat[r] * w1[r * 64 + lane];
        float h1 = silu_f(s);

        float s2 = b2[lane];
        #pragma unroll 8
        for (int k = 0; k < 64; ++k)
            s2 += __shfl(h1, k, 64) * w2[k * 64 + lane];

        float p = silu_f(s2) * w3[lane];
        p = wave_reduce(p);              // valid on lane 0
        if (which == 0) oq = p; else oe = p;
    }

    if (lane == 0) {
        pxyzq[i] = make_float4(pix, piy, piz, oq + cb3[0]);
        esr[i]   = oe + eb3[0];
    }
}

// ---------------------------------------------------------------------------
// k2: pair pass + finalize, block per atom i. The j-loop accumulates
//   s_i = sum' qr_j/r_ij, t_i = sum' 1/r_ij, qs = sum_j qr_j  (free: pj.w
//   is already loaded). Every block derives the bitwise-identical
//   c = -qs/N (same summation order), so per-atom outputs are consistent:
//   out[1+i] = qr_i + c
//   atomicAdd(out[0], 0.5*qc_i*(s_i + c*t_i) + esr[i])   // == reference E
// No cross-block handoff, no fences (round-4 lesson), no k3 node.
// ---------------------------------------------------------------------------
__global__ __launch_bounds__(NT) void k2_pair_final(const float4* __restrict__ pxyzq,
                                                    const float* __restrict__ esr,
                                                    float* __restrict__ out)
{
    __shared__ float ws[4][3];
    const int i = blockIdx.x, tid = threadIdx.x, lane = tid & 63, wv = tid >> 6;
    const float4 pi = pxyzq[i];
    float s = 0.0f, t = 0.0f, qs = 0.0f;
    for (int j = tid; j < NA; j += NT) {
        float4 pj = pxyzq[j];
        qs += pj.w;
        float dx = pi.x - pj.x, dy = pi.y - pj.y, dz = pi.z - pj.z;
        float d2 = dx*dx + dy*dy + dz*dz;
        if (j != i) {
            float rinv = rsqrtf(d2);
            t += rinv;
            s += pj.w * rinv;
        }
    }
    s  = wave_reduce(s);
    t  = wave_reduce(t);
    qs = wave_reduce(qs);
    if (lane == 0) { ws[wv][0] = s; ws[wv][1] = t; ws[wv][2] = qs; }
    __syncthreads();
    if (tid == 0) {
        float sb = ws[0][0] + ws[1][0] + ws[2][0] + ws[3][0];
        float tb = ws[0][1] + ws[1][1] + ws[2][1] + ws[3][1];
        float qb = ws[0][2] + ws[1][2] + ws[2][2] + ws[3][2];
        float c  = -qb * (1.0f / (float)NA);
        float qc = pi.w + c;
        out[1 + i] = qc;
        atomicAdd(out, 0.5f * qc * (sb + c * tb) + esr[i]);
    }
}

extern "C" void kernel_launch(void* const* d_in, const int* in_sizes, int n_in,
                              void* d_out, int out_size, void* d_ws, size_t ws_size,
                              hipStream_t stream) {
    const float* pos = (const float*)d_in[0];
    const float* cw1 = (const float*)d_in[1];
    const float* cb1 = (const float*)d_in[2];
    const float* cw2 = (const float*)d_in[3];
    const float* cb2 = (const float*)d_in[4];
    const float* cw3 = (const float*)d_in[5];
    const float* cb3 = (const float*)d_in[6];
    const float* ew1 = (const float*)d_in[7];
    const float* eb1 = (const float*)d_in[8];
    const float* ew2 = (const float*)d_in[9];
    const float* eb2 = (const float*)d_in[10];
    const float* ew3 = (const float*)d_in[11];
    const float* eb3 = (const float*)d_in[12];
    float* out = (float*)d_out;

    float4* pxyzq = (float4*)d_ws;                  // 2048 float4
    float*  esr   = (float*)(pxyzq + NA);           // 2048

    k1_feat_mlp<<<NA / 4, NT, 0, stream>>>(pos,
                                           cw1, cb1, cw2, cb2, cw3, cb3,
                                           ew1, eb1, ew2, eb2, ew3, eb3,
                                           pxyzq, esr, out);
    k2_pair_final<<<NA, NT, 0, stream>>>(pxyzq, esr, out);
}

// Round 7
// 109.859 us; speedup vs baseline: 1.1956x; 1.1956x over previous
//
#include <hip/hip_runtime.h>

#define NA 2048
#define NT 256

__device__ __forceinline__ float silu_f(float x) { return x / (1.0f + __expf(-x)); }

__device__ __forceinline__ float wave_reduce(float v) {
    #pragma unroll
    for (int off = 32; off > 0; off >>= 1) v += __shfl_down(v, off, 64);
    return v;
}

// ---------------------------------------------------------------------------
// k1: RBF features + both MLPs, one wave per atom, barrier-free.
// 512 blocks x 256 threads; wave wv of block b owns atom i = b*4 + wv.
// ---------------------------------------------------------------------------
__global__ __launch_bounds__(NT) void k1_feat_mlp(
    const float* __restrict__ pos,
    const float* __restrict__ cw1, const float* __restrict__ cb1,
    const float* __restrict__ cw2, const float* __restrict__ cb2,
    const float* __restrict__ cw3, const float* __restrict__ cb3,
    const float* __restrict__ ew1, const float* __restrict__ eb1,
    const float* __restrict__ ew2, const float* __restrict__ eb2,
    const float* __restrict__ ew3, const float* __restrict__ eb3,
    float4* __restrict__ pxyzq, float* __restrict__ esr)
{
    const int tid = threadIdx.x, lane = tid & 63, wv = tid >> 6;
    const int i = blockIdx.x * 4 + wv;
    const float pix = pos[3*i], piy = pos[3*i+1], piz = pos[3*i+2];

    float acc[16];
    #pragma unroll
    for (int r = 0; r < 16; ++r) acc[r] = 0.0f;

    for (int j = lane; j < NA; j += 64) {
        float dx = pix - pos[3*j], dy = piy - pos[3*j+1], dz = piz - pos[3*j+2];
        float d2 = dx*dx + dy*dy + dz*dz;
        if (d2 > 0.0f && d2 < 25.0f) {
            float d  = sqrtf(d2);
            float sm = 0.5f * (1.0f + __cosf(0.6283185307179586f * d)); // cos(pi*d/5)
            #pragma unroll
            for (int r = 0; r < 16; ++r) {
                float t = d - (0.5f + 0.3f * (float)r);   // centers linspace(0.5,5,16)
                acc[r] += sm * __expf(-t * t * 25.28395061728395f); // 1/(2 eta^2)
            }
        }
    }

    // reduce to lane 0 then broadcast: every lane gets the full feature vector
    float feat[16];
    #pragma unroll
    for (int r = 0; r < 16; ++r) {
        float v = wave_reduce(acc[r]);
        feat[r] = __shfl(v, 0, 64);
    }

    // both MLPs sequentially; lane = hidden unit index
    float oq = 0.0f, oe = 0.0f;
    #pragma unroll
    for (int which = 0; which < 2; ++which) {
        const float* w1 = which ? ew1 : cw1;
        const float* b1 = which ? eb1 : cb1;
        const float* w2 = which ? ew2 : cw2;
        const float* b2 = which ? eb2 : cb2;
        const float* w3 = which ? ew3 : cw3;

        float s = b1[lane];
        #pragma unroll
        for (int r = 0; r < 16; ++r) s += feat[r] * w1[r * 64 + lane];
        float h1 = silu_f(s);

        float s2 = b2[lane];
        #pragma unroll 8
        for (int k = 0; k < 64; ++k)
            s2 += __shfl(h1, k, 64) * w2[k * 64 + lane];

        float p = silu_f(s2) * w3[lane];
        p = wave_reduce(p);              // valid on lane 0
        if (which == 0) oq = p; else oe = p;
    }

    if (lane == 0) {
        pxyzq[i] = make_float4(pix, piy, piz, oq + cb3[0]);
        esr[i]   = oe + eb3[0];
    }
}

// ---------------------------------------------------------------------------
// k2: pair pass, block per atom i. j-loop accumulates
//   s_i = sum' qr_j/r_ij, t_i = sum' 1/r_ij, qs = sum_j qr_j (free add).
// Every block derives the bitwise-identical c = -qs/N (same summation
// order), writes the corrected charge out[1+i] and the complete per-atom
// energy partial earr[i] = 0.5*qc_i*(s_i + c*t_i) + esr[i].
// PLAIN STORES ONLY — rounds 4/6 showed per-block device-scope atomics or
// fences at 2048-block scale cost 24-45 us, far more than one node boundary.
// ---------------------------------------------------------------------------
__global__ __launch_bounds__(NT) void k2_pair(const float4* __restrict__ pxyzq,
                                              const float* __restrict__ esr,
                                              float* __restrict__ earr,
                                              float* __restrict__ out)
{
    __shared__ float ws[4][3];
    const int i = blockIdx.x, tid = threadIdx.x, lane = tid & 63, wv = tid >> 6;
    const float4 pi = pxyzq[i];
    float s = 0.0f, t = 0.0f, qs = 0.0f;
    for (int j = tid; j < NA; j += NT) {
        float4 pj = pxyzq[j];
        qs += pj.w;
        float dx = pi.x - pj.x, dy = pi.y - pj.y, dz = pi.z - pj.z;
        float d2 = dx*dx + dy*dy + dz*dz;
        if (j != i) {
            float rinv = rsqrtf(d2);
            t += rinv;
            s += pj.w * rinv;
        }
    }
    s  = wave_reduce(s);
    t  = wave_reduce(t);
    qs = wave_reduce(qs);
    if (lane == 0) { ws[wv][0] = s; ws[wv][1] = t; ws[wv][2] = qs; }
    __syncthreads();
    if (tid == 0) {
        float sb = ws[0][0] + ws[1][0] + ws[2][0] + ws[3][0];
        float tb = ws[0][1] + ws[1][1] + ws[2][1] + ws[3][1];
        float qb = ws[0][2] + ws[1][2] + ws[2][2] + ws[3][2];
        float c  = -qb * (1.0f / (float)NA);
        float qc = pi.w + c;
        out[1 + i] = qc;
        earr[i]    = 0.5f * qc * (sb + c * tb) + esr[i];
    }
}

// ---------------------------------------------------------------------------
// k3: minimal finalize — sum 2048 per-atom energy partials into out[0].
// ---------------------------------------------------------------------------
__global__ __launch_bounds__(NT) void k3_final(const float* __restrict__ earr,
                                               float* __restrict__ out)
{
    __shared__ float wred[4];
    const int tid = threadIdx.x, lane = tid & 63, wv = tid >> 6;
    float pe = 0.0f;
    for (int i = tid; i < NA; i += NT) pe += earr[i];
    pe = wave_reduce(pe);
    if (lane == 0) wred[wv] = pe;
    __syncthreads();
    if (tid == 0) out[0] = wred[0] + wred[1] + wred[2] + wred[3];
}

extern "C" void kernel_launch(void* const* d_in, const int* in_sizes, int n_in,
                              void* d_out, int out_size, void* d_ws, size_t ws_size,
                              hipStream_t stream) {
    const float* pos = (const float*)d_in[0];
    const float* cw1 = (const float*)d_in[1];
    const float* cb1 = (const float*)d_in[2];
    const float* cw2 = (const float*)d_in[3];
    const float* cb2 = (const float*)d_in[4];
    const float* cw3 = (const float*)d_in[5];
    const float* cb3 = (const float*)d_in[6];
    const float* ew1 = (const float*)d_in[7];
    const float* eb1 = (const float*)d_in[8];
    const float* ew2 = (const float*)d_in[9];
    const float* eb2 = (const float*)d_in[10];
    const float* ew3 = (const float*)d_in[11];
    const float* eb3 = (const float*)d_in[12];
    float* out = (float*)d_out;

    float4* pxyzq = (float4*)d_ws;                  // 2048 float4
    float*  esr   = (float*)(pxyzq + NA);           // 2048
    float*  earr  = esr + NA;                       // 2048

    k1_feat_mlp<<<NA / 4, NT, 0, stream>>>(pos,
                                           cw1, cb1, cw2, cb2, cw3, cb3,
                                           ew1, eb1, ew2, eb2, ew3, eb3,
                                           pxyzq, esr);
    k2_pair<<<NA, NT, 0, stream>>>(pxyzq, esr, earr, out);
    k3_final<<<1, NT, 0, stream>>>(earr, out);
}